// Round 6
// baseline (195.713 us; speedup 1.0000x reference)
//
#include <hip/hip_runtime.h>
#include <hip/hip_bf16.h>

// MemNet fused op, MI355X gfx950.
// T=4096, D=128, B=8192, OUT=1000.
// Pipeline: prep (bf16 cast + LDS-tiled transpose) -> norms (MFMA, row sumsq)
// -> attn (recompute scores, exp, hv MFMA) -> scores (comb fused + fp32 W-GEMM)
// -> logsoftmax in-place.
// k_norms/k_attn use 2-phase double-buffered staging: one barrier per K-tile,
// global loads issued early and ds_written late (T3-min + T14-lite).

#define T_DIM 4096
#define D_DIM 128
#define B_DIM 8192
#define OUT_DIM 1000

typedef __bf16 bf16x8 __attribute__((ext_vector_type(8)));
typedef float f32x4 __attribute__((ext_vector_type(4)));
typedef unsigned short u16x8 __attribute__((ext_vector_type(8)));
typedef unsigned short u16x4 __attribute__((ext_vector_type(4)));

#define MFMA __builtin_amdgcn_mfma_f32_16x16x32_bf16

__device__ inline bf16x8 load_cvt8(const float* __restrict__ p) {
  const float4* q = (const float4*)p;
  float4 a = q[0], b = q[1];
  bf16x8 r;
  r[0] = (__bf16)a.x; r[1] = (__bf16)a.y; r[2] = (__bf16)a.z; r[3] = (__bf16)a.w;
  r[4] = (__bf16)b.x; r[5] = (__bf16)b.y; r[6] = (__bf16)b.z; r[7] = (__bf16)b.w;
  return r;
}

__device__ inline unsigned short bfb(float f) {
  __bf16 b = (__bf16)f;
  return __builtin_bit_cast(unsigned short, b);
}

// ---------------------------------------------------------------- k_prep
// history f32 [T][D] -> hist_b bf16 [T][D] (coalesced) and histT_b bf16 [D][T]
// (LDS-tiled transpose: each 64B line of histT written whole by one thread).
// grid 128 blocks x 32 t-rows, block 256.
__global__ __launch_bounds__(256) void k_prep(const float* __restrict__ hist,
                                              __bf16* __restrict__ hist_b,
                                              __bf16* __restrict__ histT_b) {
  __shared__ float tile[32 * 132];   // stride 132 floats (528B, 16B-mult)
  const int tid = threadIdx.x;
  const int t0 = blockIdx.x * 32;
#pragma unroll
  for (int j = 0; j < 4; ++j) {
    int g = tid + j * 256;           // 1024 float4 = 32x128
    int row = g >> 5, c4 = g & 31;
    float4 v = ((const float4*)(hist + (t0 + row) * 128))[c4];
    ((float4*)(tile + row * 132))[c4] = v;
    u16x4 o = {bfb(v.x), bfb(v.y), bfb(v.z), bfb(v.w)};
    *(u16x4*)(hist_b + (t0 + row) * 128 + c4 * 4) = o;
  }
  __syncthreads();
  const int d = tid >> 1, th2 = (tid & 1) * 16;   // 16 t per thread
  u16x8 o0, o1;
#pragma unroll
  for (int i = 0; i < 8; ++i) o0[i] = bfb(tile[(th2 + i) * 132 + d]);
#pragma unroll
  for (int i = 0; i < 8; ++i) o1[i] = bfb(tile[(th2 + 8 + i) * 132 + d]);
  *(u16x8*)(histT_b + d * T_DIM + t0 + th2) = o0;
  *(u16x8*)(histT_b + d * T_DIM + t0 + th2 + 8) = o1;
}

// ---------------------------------------------------------------- k_norms
// S^T[t][b] = sum_d hist[t][d]*img[b][d]; accumulate ss[b] = sum_t s^2.
// grid (64 b-blocks of 128, 4 t-chunks of 1024), block 512 (8 waves x 16 b).
// 2-phase: double-buffered hist tile, 1 barrier/iter.
__global__ __launch_bounds__(512) void k_norms(const float* __restrict__ img,
                                               const __bf16* __restrict__ hist_b,
                                               float* __restrict__ sspart) {
  __shared__ __bf16 hist_lds[2 * 32 * 128];   // 2 x 8KB, XOR-swizzled rows
  const int rb = blockIdx.x, tc = blockIdx.y;
  const int tid = threadIdx.x;
  const int wave = tid >> 6, lane = tid & 63, bl = lane & 15, lg = lane >> 4;
  const int b0 = rb * 128 + wave * 16;

  // img B-fragments (K=128 -> 4 frags): B[k=d][n=b]
  bf16x8 bfrag[4];
#pragma unroll
  for (int kf = 0; kf < 4; ++kf)
    bfrag[kf] = load_cvt8(img + (b0 + bl) * 128 + kf * 32 + lg * 8);

  const int sr = tid >> 4;            // staging row 0..31
  const int sc = (tid & 15) * 8;      // staging col (elems), 16B per thread
  char* const ldsb = (char*)hist_lds;
  const int w0 = (sr * 256 + sc * 2) ^ ((sr & 7) << 4);
  const int tbase = tc * 1024;

  // prologue: stage tile 0 into buf0
  *(u16x8*)(ldsb + w0) = *(const u16x8*)(hist_b + (tbase + sr) * 128 + sc);
  __syncthreads();

  float ss = 0.f;
  for (int it = 0; it < 32; ++it) {
    // issue next-tile load early (clamped; last iter redundant but harmless)
    const int itn = it + 1 < 32 ? it + 1 : 31;
    const u16x8 nx = *(const u16x8*)(hist_b + (tbase + itn * 32 + sr) * 128 + sc);
    char* const rb_ = ldsb + (it & 1) * 8192;

    f32x4 acc0 = {0.f, 0.f, 0.f, 0.f}, acc1 = {0.f, 0.f, 0.f, 0.f};
#pragma unroll
    for (int kf = 0; kf < 4; ++kf) {
      const int c2 = (kf * 32 + lg * 8) * 2;
      bf16x8 a0 = *(const bf16x8*)(rb_ + ((bl * 256 + c2) ^ ((bl & 7) << 4)));
      bf16x8 a1 = *(const bf16x8*)(rb_ + (((16 + bl) * 256 + c2) ^ ((bl & 7) << 4)));
      acc0 = MFMA(a0, bfrag[kf], acc0, 0, 0, 0);
      acc1 = MFMA(a1, bfrag[kf], acc1, 0, 0, 0);
    }
#pragma unroll
    for (int r = 0; r < 4; ++r) {
      ss = fmaf(acc0[r], acc0[r], ss);
      ss = fmaf(acc1[r], acc1[r], ss);
    }
    // write next tile into the other buffer, then one barrier
    *(u16x8*)(ldsb + ((it + 1) & 1) * 8192 + w0) = nx;
    __syncthreads();
  }
  // lane holds b = b0+bl; sum the 4 lane-groups (t-rows)
  ss += __shfl_xor(ss, 16);
  ss += __shfl_xor(ss, 32);
  if (lane < 16) sspart[tc * B_DIM + b0 + lane] = ss;
}

// ---------------------------------------------------------------- k_attn
// Recompute S^T per 32-t tile, z=exp(s/norm), hv += z*hist, Z += z.
// grid (64 b-blocks of 128, 4 t-chunks of 1024), block 512 (8 waves x 16 b).
// 2-phase: double-buffered hist/histT tiles, 1 barrier/iter; z wave-private.
__global__ __launch_bounds__(512) void k_attn(const float* __restrict__ img,
                                              const __bf16* __restrict__ hist_b,
                                              const __bf16* __restrict__ histT_b,
                                              const float* __restrict__ sspart,
                                              float* __restrict__ hvpart,
                                              float* __restrict__ zpart) {
  __shared__ __align__(16) char smem[2 * 8192 + 2 * 8192 + 8192 + 512];
  char* const h_base  = smem;                        // hist tiles [2][32t][128d]
  char* const ht_base = smem + 16384;                // histT tiles [2][128d][32t]
  __bf16* const z_base = (__bf16*)(smem + 32768);    // [8 waves][16b][32t]
  float* const rnorm_lds = (float*)(smem + 40960);   // [128]

  const int rb = blockIdx.x, th = blockIdx.y;
  const int tid = threadIdx.x;
  const int wave = tid >> 6, lane = tid & 63, bl = lane & 15, lg = lane >> 4;
  const int b0 = rb * 128 + wave * 16;

  if (tid < 128) {
    int b = rb * 128 + tid;
    float s = sspart[b] + sspart[B_DIM + b] + sspart[2 * B_DIM + b] + sspart[3 * B_DIM + b];
    rnorm_lds[tid] = 1.0f / sqrtf(s);
  }

  bf16x8 bfrag[4];
#pragma unroll
  for (int kf = 0; kf < 4; ++kf)
    bfrag[kf] = load_cvt8(img + (b0 + bl) * 128 + kf * 32 + lg * 8);

  // staging: 512 threads, 16B hist + 16B histT each
  const int sr = tid >> 4, sc = (tid & 15) * 8;   // hist tile 32x128
  const int td = tid >> 2, tt2 = (tid & 3) * 8;   // histT tile 128x32
  const int hw0 = (sr * 256 + sc * 2) ^ ((sr & 7) << 4);
  const int tw0 = (td * 64 + tt2 * 2) ^ ((td & 7) << 4);
  char* const z_b = (char*)(z_base + wave * 512);
  const int tbase = th * 1024;

  // prologue: stage tile 0 into buf0 (also publishes rnorm_lds)
  *(u16x8*)(h_base + hw0)  = *(const u16x8*)(hist_b + (tbase + sr) * 128 + sc);
  *(u16x8*)(ht_base + tw0) = *(const u16x8*)(histT_b + td * T_DIM + tbase + tt2);
  __syncthreads();
  const float rn = rnorm_lds[wave * 16 + bl];   // score acc col = b = bl

  f32x4 hv[8];
#pragma unroll
  for (int i = 0; i < 8; ++i) hv[i] = (f32x4){0.f, 0.f, 0.f, 0.f};
  float zs = 0.f;

  for (int it = 0; it < 32; ++it) {
    // issue next-tile global loads early; they complete under the compute
    const int itn = it + 1 < 32 ? it + 1 : 31;
    const int tn = tbase + itn * 32;
    const u16x8 nh = *(const u16x8*)(hist_b + (tn + sr) * 128 + sc);
    const u16x8 nt = *(const u16x8*)(histT_b + td * T_DIM + tn + tt2);
    char* const h_b  = h_base + (it & 1) * 8192;
    char* const ht_b = ht_base + (it & 1) * 8192;

    // scores S^T: A = hist tile (m=t), B = img frags (n=b)
    f32x4 s0 = {0.f, 0.f, 0.f, 0.f}, s1v = {0.f, 0.f, 0.f, 0.f};
#pragma unroll
    for (int kf = 0; kf < 4; ++kf) {
      const int c2 = (kf * 32 + lg * 8) * 2;
      bf16x8 a0 = *(const bf16x8*)(h_b + ((bl * 256 + c2) ^ ((bl & 7) << 4)));
      bf16x8 a1 = *(const bf16x8*)(h_b + (((16 + bl) * 256 + c2) ^ ((bl & 7) << 4)));
      s0 = MFMA(a0, bfrag[kf], s0, 0, 0, 0);
      s1v = MFMA(a1, bfrag[kf], s1v, 0, 0, 0);
    }
    // z = exp(s*rn); |s*rn| <= 1 after L2-norm, no max-subtraction needed.
    // score acc: b = bl, t = tt*16 + lg*4 + r. Pack t-pairs into z_lds.
#pragma unroll
    for (int tt = 0; tt < 2; ++tt) {
      f32x4 s = tt ? s1v : s0;
#pragma unroll
      for (int rp = 0; rp < 2; ++rp) {
        float z0 = __expf(s[2 * rp] * rn);
        float z1 = __expf(s[2 * rp + 1] * rn);
        unsigned int pk = (unsigned)bfb(z0) | ((unsigned)bfb(z1) << 16);
        int t = tt * 16 + lg * 4 + 2 * rp;
        *(unsigned int*)(z_b + ((bl * 64 + t * 2) ^ ((bl & 7) << 4))) = pk;
      }
    }
    // z_b is wave-private: same-wave ds_write->ds_read ordered by lgkmcnt;
    // per-lane write/read byte ranges overlap, so the compiler cannot
    // reorder, and DS ops from one wave are processed in issue order.
    // z A-frag: A[m=b][k=t]: lane holds m=bl, t=lg*8+i
    bf16x8 zf = *(const bf16x8*)(z_b + ((bl * 64 + lg * 16) ^ ((bl & 7) << 4)));
#pragma unroll
    for (int i = 0; i < 8; ++i) zs += (float)zf[i];
    // hv: B[k=t][n=d] from histT tile
#pragma unroll
    for (int dt = 0; dt < 8; ++dt) {
      const int d = dt * 16 + bl;
      bf16x8 bf = *(const bf16x8*)(ht_b + ((d * 64 + lg * 16) ^ ((d & 7) << 4)));
      hv[dt] = MFMA(zf, bf, hv[dt], 0, 0, 0);
    }

    // write next tile into the other buffers, then the single barrier.
    // Safe: buffer X is read in iter i (drained at barrier i), written in
    // iter i+1 strictly after barrier i.
    *(u16x8*)(h_base + ((it + 1) & 1) * 8192 + hw0)  = nh;
    *(u16x8*)(ht_base + ((it + 1) & 1) * 8192 + tw0) = nt;
    __syncthreads();
  }

  // hv acc: row=(lg*4+r) -> b, col=bl -> d (within dt tile)
#pragma unroll
  for (int dt = 0; dt < 8; ++dt)
#pragma unroll
    for (int r = 0; r < 4; ++r)
      hvpart[(size_t)th * (B_DIM * 128) + (size_t)(b0 + lg * 4 + r) * 128 + dt * 16 + bl] = hv[dt][r];
  zs += __shfl_xor(zs, 16);
  zs += __shfl_xor(zs, 32);
  if (lane < 16) zpart[th * B_DIM + b0 + lane] = zs;
}

// ---------------------------------------------------------------- k_scores
// comb = sum_th hv/Z + img (fused), then fp32 GEMM: each thread owns one
// out-column (W row in 128 VGPRs), comb rows broadcast from LDS.
// grid (128 b-blocks of 64, 4 out-blocks of 256), block 256.
__global__ __launch_bounds__(256) void k_scores(const float* __restrict__ img,
                                                const float* __restrict__ hvpart,
                                                const float* __restrict__ zpart,
                                                const float* __restrict__ W,
                                                const float* __restrict__ bias,
                                                float* __restrict__ out) {
  __shared__ float c_lds[64 * 128];   // 32KB
  __shared__ float zs_lds[64];
  const int rb = blockIdx.x, ob = blockIdx.y;
  const int tid = threadIdx.x;
  const int r0 = rb * 64;
  const int o = ob * 256 + tid;
  const bool act = o < OUT_DIM;
  const int osafe = act ? o : 0;

  if (tid < 64) {
    int b = r0 + tid;
    zs_lds[tid] = zpart[b] + zpart[B_DIM + b] + zpart[2 * B_DIM + b] + zpart[3 * B_DIM + b];
  }

  float4 w[32];
  {
    const float4* wp = (const float4*)(W + osafe * 128);
#pragma unroll
    for (int i = 0; i < 32; ++i) w[i] = wp[i];
  }
  const float bv = bias[osafe];
  __syncthreads();   // zs_lds ready

#pragma unroll
  for (int j = 0; j < 8; ++j) {
    int g = tid + j * 256;              // 2048 float4 = 64x128
    int row = g >> 5, c4 = g & 31;
    size_t idx = (size_t)(r0 + row) * 128 + c4 * 4;
    float4 h0 = ((const float4*)hvpart)[idx / 4];
    float4 h1 = ((const float4*)(hvpart + (size_t)B_DIM * 128))[idx / 4];
    float4 h2 = ((const float4*)(hvpart + (size_t)2 * B_DIM * 128))[idx / 4];
    float4 h3 = ((const float4*)(hvpart + (size_t)3 * B_DIM * 128))[idx / 4];
    float4 im = ((const float4*)img)[idx / 4];
    float rz = 1.0f / zs_lds[row];
    float4 c;
    c.x = (h0.x + h1.x + h2.x + h3.x) * rz + im.x;
    c.y = (h0.y + h1.y + h2.y + h3.y) * rz + im.y;
    c.z = (h0.z + h1.z + h2.z + h3.z) * rz + im.z;
    c.w = (h0.w + h1.w + h2.w + h3.w) * rz + im.w;
    ((float4*)c_lds)[row * 32 + c4] = c;
  }
  __syncthreads();

  for (int r = 0; r < 64; ++r) {
    const float4* c4 = (const float4*)(c_lds + r * 128);
    float a0 = 0.f, a1 = 0.f, a2 = 0.f, a3 = 0.f;
#pragma unroll
    for (int k = 0; k < 32; k += 4) {
      float4 x0 = c4[k], x1 = c4[k + 1], x2 = c4[k + 2], x3 = c4[k + 3];
      a0 = fmaf(w[k].x, x0.x, a0);     a0 = fmaf(w[k].y, x0.y, a0);
      a0 = fmaf(w[k].z, x0.z, a0);     a0 = fmaf(w[k].w, x0.w, a0);
      a1 = fmaf(w[k + 1].x, x1.x, a1); a1 = fmaf(w[k + 1].y, x1.y, a1);
      a1 = fmaf(w[k + 1].z, x1.z, a1); a1 = fmaf(w[k + 1].w, x1.w, a1);
      a2 = fmaf(w[k + 2].x, x2.x, a2); a2 = fmaf(w[k + 2].y, x2.y, a2);
      a2 = fmaf(w[k + 2].z, x2.z, a2); a2 = fmaf(w[k + 2].w, x2.w, a2);
      a3 = fmaf(w[k + 3].x, x3.x, a3); a3 = fmaf(w[k + 3].y, x3.y, a3);
      a3 = fmaf(w[k + 3].z, x3.z, a3); a3 = fmaf(w[k + 3].w, x3.w, a3);
    }
    if (act) out[(size_t)(r0 + r) * OUT_DIM + o] = bv + ((a0 + a1) + (a2 + a3));
  }
}

// ---------------------------------------------------------------- k_lsm
// in-place log_softmax over OUT per row; one wave per row
__global__ __launch_bounds__(256) void k_lsm(float* __restrict__ out) {
  const int row = blockIdx.x * 4 + (threadIdx.x >> 6);
  const int lane = threadIdx.x & 63;
  float v[16];
  float mx = -3.4e38f;
#pragma unroll
  for (int i = 0; i < 16; ++i) {
    int o2 = i * 64 + lane;
    v[i] = (o2 < OUT_DIM) ? out[(size_t)row * OUT_DIM + o2] : -3.4e38f;
    mx = fmaxf(mx, v[i]);
  }
#pragma unroll
  for (int s = 1; s < 64; s <<= 1) mx = fmaxf(mx, __shfl_xor(mx, s));
  float sum = 0.f;
#pragma unroll
  for (int i = 0; i < 16; ++i) sum += __expf(v[i] - mx);
#pragma unroll
  for (int s = 1; s < 64; s <<= 1) sum += __shfl_xor(sum, s);
  const float lse = mx + __logf(sum);
#pragma unroll
  for (int i = 0; i < 16; ++i) {
    int o2 = i * 64 + lane;
    if (o2 < OUT_DIM) out[(size_t)row * OUT_DIM + o2] = v[i] - lse;
  }
}

extern "C" void kernel_launch(void* const* d_in, const int* in_sizes, int n_in,
                              void* d_out, int out_size, void* d_ws, size_t ws_size,
                              hipStream_t stream) {
  const float* hist = (const float*)d_in[0];   // [4096][128]
  const float* img  = (const float*)d_in[1];   // [8192][128]
  const float* W    = (const float*)d_in[2];   // [1000][128]
  const float* bias = (const float*)d_in[3];   // [1000]
  float* out = (float*)d_out;                  // [8192][1000]

  char* ws = (char*)d_ws;
  // ws layout (~18.3 MiB):
  __bf16* hist_b  = (__bf16*)(ws);                         // 1 MiB
  __bf16* histT_b = (__bf16*)(ws + (1 << 20));             // 1 MiB
  float* sspart   = (float*)(ws + (2 << 20));              // 128 KiB [4][B]
  float* zpart    = (float*)(ws + (2 << 20) + (128 << 10));// 128 KiB [4][B]
  float* hvpart   = (float*)(ws + (2 << 20) + (256 << 10));// 16 MiB  [4][B][128]

  k_prep<<<dim3(128), dim3(256), 0, stream>>>(hist, hist_b, histT_b);
  k_norms<<<dim3(64, 4), dim3(512), 0, stream>>>(img, hist_b, sspart);
  k_attn<<<dim3(64, 4), dim3(512), 0, stream>>>(img, hist_b, histT_b, sspart, hvpart, zpart);
  k_scores<<<dim3(128, 4), dim3(256), 0, stream>>>(img, hvpart, zpart, W, bias, out);
  k_lsm<<<dim3(2048), dim3(256), 0, stream>>>(out);
}

// Round 10
// 149.488 us; speedup vs baseline: 1.3092x; 1.3092x over previous
//
#include <hip/hip_runtime.h>
#include <hip/hip_bf16.h>

// MemNet fused op, MI355X gfx950.
// T=4096, D=128, B=8192, OUT=1000.
// Pipeline: prep (bf16 cast + transpose) + wprep (W split-bf16) -> norms
// -> attn -> scores2 (comb fused + split-bf16 3-MFMA GEMM + fused log-softmax).
// R6: k_scores was LDS-broadcast-issue bound (2048 ds_read_b128/wave, ~75us).
// Replaced with MFMA GEMM (16 ds_read_b128/wave) + fused lsm epilogue.

#define T_DIM 4096
#define D_DIM 128
#define B_DIM 8192
#define OUT_DIM 1000

typedef __bf16 bf16x8 __attribute__((ext_vector_type(8)));
typedef float f32x4 __attribute__((ext_vector_type(4)));
typedef unsigned short u16x8 __attribute__((ext_vector_type(8)));
typedef unsigned short u16x4 __attribute__((ext_vector_type(4)));

#define MFMA __builtin_amdgcn_mfma_f32_16x16x32_bf16

__device__ inline bf16x8 load_cvt8(const float* __restrict__ p) {
  const float4* q = (const float4*)p;
  float4 a = q[0], b = q[1];
  bf16x8 r;
  r[0] = (__bf16)a.x; r[1] = (__bf16)a.y; r[2] = (__bf16)a.z; r[3] = (__bf16)a.w;
  r[4] = (__bf16)b.x; r[5] = (__bf16)b.y; r[6] = (__bf16)b.z; r[7] = (__bf16)b.w;
  return r;
}

__device__ inline unsigned short bfb(float f) {
  __bf16 b = (__bf16)f;
  return __builtin_bit_cast(unsigned short, b);
}

// ---------------------------------------------------------------- k_prep
__global__ __launch_bounds__(256) void k_prep(const float* __restrict__ hist,
                                              __bf16* __restrict__ hist_b,
                                              __bf16* __restrict__ histT_b) {
  __shared__ float tile[32 * 132];   // stride 132 floats (528B, 16B-mult)
  const int tid = threadIdx.x;
  const int t0 = blockIdx.x * 32;
#pragma unroll
  for (int j = 0; j < 4; ++j) {
    int g = tid + j * 256;           // 1024 float4 = 32x128
    int row = g >> 5, c4 = g & 31;
    float4 v = ((const float4*)(hist + (t0 + row) * 128))[c4];
    ((float4*)(tile + row * 132))[c4] = v;
    u16x4 o = {bfb(v.x), bfb(v.y), bfb(v.z), bfb(v.w)};
    *(u16x4*)(hist_b + (t0 + row) * 128 + c4 * 4) = o;
  }
  __syncthreads();
  const int d = tid >> 1, th2 = (tid & 1) * 16;   // 16 t per thread
  u16x8 o0, o1;
#pragma unroll
  for (int i = 0; i < 8; ++i) o0[i] = bfb(tile[(th2 + i) * 132 + d]);
#pragma unroll
  for (int i = 0; i < 8; ++i) o1[i] = bfb(tile[(th2 + 8 + i) * 132 + d]);
  *(u16x8*)(histT_b + d * T_DIM + t0 + th2) = o0;
  *(u16x8*)(histT_b + d * T_DIM + t0 + th2 + 8) = o1;
}

// ---------------------------------------------------------------- k_wprep
// W f32 [1000][128] -> W_hi bf16 + W_lo bf16 (residual). 128000 elems, grid 125.
__global__ __launch_bounds__(256) void k_wprep(const float* __restrict__ W,
                                               __bf16* __restrict__ W_hi,
                                               __bf16* __restrict__ W_lo) {
  const int idx = (blockIdx.x * 256 + threadIdx.x) * 4;
  float4 v = *(const float4*)(W + idx);
  u16x4 hi, lo;
  float h;
  h = (float)(__bf16)v.x; hi[0] = bfb(v.x); lo[0] = bfb(v.x - h);
  h = (float)(__bf16)v.y; hi[1] = bfb(v.y); lo[1] = bfb(v.y - h);
  h = (float)(__bf16)v.z; hi[2] = bfb(v.z); lo[2] = bfb(v.z - h);
  h = (float)(__bf16)v.w; hi[3] = bfb(v.w); lo[3] = bfb(v.w - h);
  *(u16x4*)(W_hi + idx) = hi;
  *(u16x4*)(W_lo + idx) = lo;
}

// ---------------------------------------------------------------- k_norms
__global__ __launch_bounds__(512) void k_norms(const float* __restrict__ img,
                                               const __bf16* __restrict__ hist_b,
                                               float* __restrict__ sspart) {
  __shared__ __bf16 hist_lds[2 * 32 * 128];   // 2 x 8KB, XOR-swizzled rows
  const int rb = blockIdx.x, tc = blockIdx.y;
  const int tid = threadIdx.x;
  const int wave = tid >> 6, lane = tid & 63, bl = lane & 15, lg = lane >> 4;
  const int b0 = rb * 128 + wave * 16;

  bf16x8 bfrag[4];
#pragma unroll
  for (int kf = 0; kf < 4; ++kf)
    bfrag[kf] = load_cvt8(img + (b0 + bl) * 128 + kf * 32 + lg * 8);

  const int sr = tid >> 4;
  const int sc = (tid & 15) * 8;
  char* const ldsb = (char*)hist_lds;
  const int w0 = (sr * 256 + sc * 2) ^ ((sr & 7) << 4);
  const int tbase = tc * 1024;

  *(u16x8*)(ldsb + w0) = *(const u16x8*)(hist_b + (tbase + sr) * 128 + sc);
  __syncthreads();

  float ss = 0.f;
  for (int it = 0; it < 32; ++it) {
    const int itn = it + 1 < 32 ? it + 1 : 31;
    const u16x8 nx = *(const u16x8*)(hist_b + (tbase + itn * 32 + sr) * 128 + sc);
    char* const rb_ = ldsb + (it & 1) * 8192;

    f32x4 acc0 = {0.f, 0.f, 0.f, 0.f}, acc1 = {0.f, 0.f, 0.f, 0.f};
#pragma unroll
    for (int kf = 0; kf < 4; ++kf) {
      const int c2 = (kf * 32 + lg * 8) * 2;
      bf16x8 a0 = *(const bf16x8*)(rb_ + ((bl * 256 + c2) ^ ((bl & 7) << 4)));
      bf16x8 a1 = *(const bf16x8*)(rb_ + (((16 + bl) * 256 + c2) ^ ((bl & 7) << 4)));
      acc0 = MFMA(a0, bfrag[kf], acc0, 0, 0, 0);
      acc1 = MFMA(a1, bfrag[kf], acc1, 0, 0, 0);
    }
#pragma unroll
    for (int r = 0; r < 4; ++r) {
      ss = fmaf(acc0[r], acc0[r], ss);
      ss = fmaf(acc1[r], acc1[r], ss);
    }
    *(u16x8*)(ldsb + ((it + 1) & 1) * 8192 + w0) = nx;
    __syncthreads();
  }
  ss += __shfl_xor(ss, 16);
  ss += __shfl_xor(ss, 32);
  if (lane < 16) sspart[tc * B_DIM + b0 + lane] = ss;
}

// ---------------------------------------------------------------- k_attn
__global__ __launch_bounds__(512) void k_attn(const float* __restrict__ img,
                                              const __bf16* __restrict__ hist_b,
                                              const __bf16* __restrict__ histT_b,
                                              const float* __restrict__ sspart,
                                              float* __restrict__ hvpart,
                                              float* __restrict__ zpart) {
  __shared__ __align__(16) char smem[2 * 8192 + 2 * 8192 + 8192 + 512];
  char* const h_base  = smem;                        // hist tiles [2][32t][128d]
  char* const ht_base = smem + 16384;                // histT tiles [2][128d][32t]
  __bf16* const z_base = (__bf16*)(smem + 32768);    // [8 waves][16b][32t]
  float* const rnorm_lds = (float*)(smem + 40960);   // [128]

  const int rb = blockIdx.x, th = blockIdx.y;
  const int tid = threadIdx.x;
  const int wave = tid >> 6, lane = tid & 63, bl = lane & 15, lg = lane >> 4;
  const int b0 = rb * 128 + wave * 16;

  if (tid < 128) {
    int b = rb * 128 + tid;
    float s = sspart[b] + sspart[B_DIM + b] + sspart[2 * B_DIM + b] + sspart[3 * B_DIM + b];
    rnorm_lds[tid] = 1.0f / sqrtf(s);
  }

  bf16x8 bfrag[4];
#pragma unroll
  for (int kf = 0; kf < 4; ++kf)
    bfrag[kf] = load_cvt8(img + (b0 + bl) * 128 + kf * 32 + lg * 8);

  const int sr = tid >> 4, sc = (tid & 15) * 8;   // hist tile 32x128
  const int td = tid >> 2, tt2 = (tid & 3) * 8;   // histT tile 128x32
  const int hw0 = (sr * 256 + sc * 2) ^ ((sr & 7) << 4);
  const int tw0 = (td * 64 + tt2 * 2) ^ ((td & 7) << 4);
  char* const z_b = (char*)(z_base + wave * 512);
  const int tbase = th * 1024;

  *(u16x8*)(h_base + hw0)  = *(const u16x8*)(hist_b + (tbase + sr) * 128 + sc);
  *(u16x8*)(ht_base + tw0) = *(const u16x8*)(histT_b + td * T_DIM + tbase + tt2);
  __syncthreads();
  const float rn = rnorm_lds[wave * 16 + bl];

  f32x4 hv[8];
#pragma unroll
  for (int i = 0; i < 8; ++i) hv[i] = (f32x4){0.f, 0.f, 0.f, 0.f};
  float zs = 0.f;

  for (int it = 0; it < 32; ++it) {
    const int itn = it + 1 < 32 ? it + 1 : 31;
    const int tn = tbase + itn * 32;
    const u16x8 nh = *(const u16x8*)(hist_b + (tn + sr) * 128 + sc);
    const u16x8 nt = *(const u16x8*)(histT_b + td * T_DIM + tn + tt2);
    char* const h_b  = h_base + (it & 1) * 8192;
    char* const ht_b = ht_base + (it & 1) * 8192;

    f32x4 s0 = {0.f, 0.f, 0.f, 0.f}, s1v = {0.f, 0.f, 0.f, 0.f};
#pragma unroll
    for (int kf = 0; kf < 4; ++kf) {
      const int c2 = (kf * 32 + lg * 8) * 2;
      bf16x8 a0 = *(const bf16x8*)(h_b + ((bl * 256 + c2) ^ ((bl & 7) << 4)));
      bf16x8 a1 = *(const bf16x8*)(h_b + (((16 + bl) * 256 + c2) ^ ((bl & 7) << 4)));
      s0 = MFMA(a0, bfrag[kf], s0, 0, 0, 0);
      s1v = MFMA(a1, bfrag[kf], s1v, 0, 0, 0);
    }
#pragma unroll
    for (int tt = 0; tt < 2; ++tt) {
      f32x4 s = tt ? s1v : s0;
#pragma unroll
      for (int rp = 0; rp < 2; ++rp) {
        float z0 = __expf(s[2 * rp] * rn);
        float z1 = __expf(s[2 * rp + 1] * rn);
        unsigned int pk = (unsigned)bfb(z0) | ((unsigned)bfb(z1) << 16);
        int t = tt * 16 + lg * 4 + 2 * rp;
        *(unsigned int*)(z_b + ((bl * 64 + t * 2) ^ ((bl & 7) << 4))) = pk;
      }
    }
    bf16x8 zf = *(const bf16x8*)(z_b + ((bl * 64 + lg * 16) ^ ((bl & 7) << 4)));
#pragma unroll
    for (int i = 0; i < 8; ++i) zs += (float)zf[i];
#pragma unroll
    for (int dt = 0; dt < 8; ++dt) {
      const int d = dt * 16 + bl;
      bf16x8 bf = *(const bf16x8*)(ht_b + ((d * 64 + lg * 16) ^ ((d & 7) << 4)));
      hv[dt] = MFMA(zf, bf, hv[dt], 0, 0, 0);
    }

    *(u16x8*)(h_base + ((it + 1) & 1) * 8192 + hw0)  = nh;
    *(u16x8*)(ht_base + ((it + 1) & 1) * 8192 + tw0) = nt;
    __syncthreads();
  }

#pragma unroll
  for (int dt = 0; dt < 8; ++dt)
#pragma unroll
    for (int r = 0; r < 4; ++r)
      hvpart[(size_t)th * (B_DIM * 128) + (size_t)(b0 + lg * 4 + r) * 128 + dt * 16 + bl] = hv[dt][r];
  zs += __shfl_xor(zs, 16);
  zs += __shfl_xor(zs, 32);
  if (lane < 16) zpart[th * B_DIM + b0 + lane] = zs;
}

// ---------------------------------------------------------------- k_scores2
// comb = sum_th hv/Z + img (fused, split bf16 hi+lo into swizzled LDS);
// scores = c_hi*W_hi + c_lo*W_hi + c_hi*W_lo via MFMA; fused log-softmax
// epilogue (row max/sumexp across the block's 8 waves), final out written once.
// grid 256 blocks (32 rows each), block 512 = 8 waves; wave w owns cols
// [w*128, w*128+128).
__global__ __launch_bounds__(512) void k_scores2(const float* __restrict__ img,
                                                 const float* __restrict__ hvpart,
                                                 const float* __restrict__ zpart,
                                                 const __bf16* __restrict__ W_hi,
                                                 const __bf16* __restrict__ W_lo,
                                                 const float* __restrict__ bias,
                                                 float* __restrict__ out) {
  __shared__ __align__(16) char smem[8192 + 8192 + 1024 + 1024];
  char* const lds_hi = smem;                       // comb_hi [32][128] bf16, swz
  char* const lds_lo = smem + 8192;                // comb_lo [32][128] bf16, swz
  float* const red_max = (float*)(smem + 16384);   // [32][8]
  float* const red_sum = (float*)(smem + 17408);   // [32][8]

  const int tid = threadIdx.x;
  const int wave = tid >> 6, lane = tid & 63, bl = lane & 15, lg = lane >> 4;
  const int r0 = blockIdx.x * 32;

  // ---- stage comb tile as split bf16 (each thread: 1 row x 8 cols)
  {
    const int row = tid >> 4;            // 0..31
    const int c0 = (tid & 15) * 8;       // col
    const int b = r0 + row;
    const float zs = zpart[b] + zpart[B_DIM + b] + zpart[2 * B_DIM + b] + zpart[3 * B_DIM + b];
    const float rz = 1.0f / zs;
    const size_t base = (size_t)b * 128 + c0;
    const float4* h0p = (const float4*)(hvpart + base);
    const float4* h1p = (const float4*)(hvpart + (size_t)B_DIM * 128 + base);
    const float4* h2p = (const float4*)(hvpart + (size_t)2 * B_DIM * 128 + base);
    const float4* h3p = (const float4*)(hvpart + (size_t)3 * B_DIM * 128 + base);
    const float4* imp = (const float4*)(img + base);
    u16x8 hi8, lo8;
#pragma unroll
    for (int q = 0; q < 2; ++q) {
      float4 h0 = h0p[q], h1 = h1p[q], h2 = h2p[q], h3 = h3p[q], im = imp[q];
      float c0f = (h0.x + h1.x + h2.x + h3.x) * rz + im.x;
      float c1f = (h0.y + h1.y + h2.y + h3.y) * rz + im.y;
      float c2f = (h0.z + h1.z + h2.z + h3.z) * rz + im.z;
      float c3f = (h0.w + h1.w + h2.w + h3.w) * rz + im.w;
      float h;
      h = (float)(__bf16)c0f; hi8[q * 4 + 0] = bfb(c0f); lo8[q * 4 + 0] = bfb(c0f - h);
      h = (float)(__bf16)c1f; hi8[q * 4 + 1] = bfb(c1f); lo8[q * 4 + 1] = bfb(c1f - h);
      h = (float)(__bf16)c2f; hi8[q * 4 + 2] = bfb(c2f); lo8[q * 4 + 2] = bfb(c2f - h);
      h = (float)(__bf16)c3f; hi8[q * 4 + 3] = bfb(c3f); lo8[q * 4 + 3] = bfb(c3f - h);
    }
    const int woff = (row * 256 + c0 * 2) ^ ((row & 7) << 4);
    *(u16x8*)(lds_hi + woff) = hi8;
    *(u16x8*)(lds_lo + woff) = lo8;
  }
  __syncthreads();

  // ---- A fragments (read once): A[m][k], lane: m = mf*16+bl, k = kf*32+lg*8+i
  bf16x8 a_hi[2][4], a_lo[2][4];
#pragma unroll
  for (int mf = 0; mf < 2; ++mf)
#pragma unroll
    for (int kf = 0; kf < 4; ++kf) {
      const int m = mf * 16 + bl;
      const int off = (m * 256 + (kf * 32 + lg * 8) * 2) ^ ((m & 7) << 4);
      a_hi[mf][kf] = *(const bf16x8*)(lds_hi + off);
      a_lo[mf][kf] = *(const bf16x8*)(lds_lo + off);
    }

  // ---- GEMM: 3-product split-bf16, W fragments straight from global (L2)
  f32x4 acc[2][8];
#pragma unroll
  for (int mf = 0; mf < 2; ++mf)
#pragma unroll
    for (int nf = 0; nf < 8; ++nf) acc[mf][nf] = (f32x4){0.f, 0.f, 0.f, 0.f};

#pragma unroll
  for (int nf = 0; nf < 8; ++nf) {
    const int col = wave * 128 + nf * 16 + bl;
    const int csafe = col < OUT_DIM ? col : OUT_DIM - 1;
    bf16x8 w_hi[4], w_lo[4];
#pragma unroll
    for (int kf = 0; kf < 4; ++kf) {
      w_hi[kf] = *(const bf16x8*)(W_hi + (size_t)csafe * 128 + kf * 32 + lg * 8);
      w_lo[kf] = *(const bf16x8*)(W_lo + (size_t)csafe * 128 + kf * 32 + lg * 8);
    }
#pragma unroll
    for (int mf = 0; mf < 2; ++mf)
#pragma unroll
      for (int kf = 0; kf < 4; ++kf) {
        acc[mf][nf] = MFMA(a_hi[mf][kf], w_hi[kf], acc[mf][nf], 0, 0, 0);
        acc[mf][nf] = MFMA(a_lo[mf][kf], w_hi[kf], acc[mf][nf], 0, 0, 0);
        acc[mf][nf] = MFMA(a_hi[mf][kf], w_lo[kf], acc[mf][nf], 0, 0, 0);
      }
  }

  // ---- epilogue: bias, then fused log-softmax over the row (1000 cols)
  // acc value (mf,nf,reg r) is at row = mf*16+lg*4+r, col = wave*128+nf*16+bl
  float bv[8];
  bool vmask[8];
#pragma unroll
  for (int nf = 0; nf < 8; ++nf) {
    const int col = wave * 128 + nf * 16 + bl;
    vmask[nf] = col < OUT_DIM;
    bv[nf] = vmask[nf] ? bias[col] : 0.f;
  }
#pragma unroll
  for (int mf = 0; mf < 2; ++mf)
#pragma unroll
    for (int nf = 0; nf < 8; ++nf)
#pragma unroll
      for (int r = 0; r < 4; ++r) acc[mf][nf][r] += bv[nf];

  // wave-local row max over this wave's 128 cols
  float rmax[2][4];
#pragma unroll
  for (int mf = 0; mf < 2; ++mf)
#pragma unroll
    for (int r = 0; r < 4; ++r) rmax[mf][r] = -3.4e38f;
#pragma unroll
  for (int mf = 0; mf < 2; ++mf)
#pragma unroll
    for (int nf = 0; nf < 8; ++nf)
#pragma unroll
      for (int r = 0; r < 4; ++r) {
        float v = vmask[nf] ? acc[mf][nf][r] : -3.4e38f;
        rmax[mf][r] = fmaxf(rmax[mf][r], v);
      }
#pragma unroll
  for (int s = 1; s < 16; s <<= 1)
#pragma unroll
    for (int mf = 0; mf < 2; ++mf)
#pragma unroll
      for (int r = 0; r < 4; ++r) rmax[mf][r] = fmaxf(rmax[mf][r], __shfl_xor(rmax[mf][r], s));
  if (bl == 0)
#pragma unroll
    for (int mf = 0; mf < 2; ++mf)
#pragma unroll
      for (int r = 0; r < 4; ++r) red_max[(mf * 16 + lg * 4 + r) * 8 + wave] = rmax[mf][r];
  __syncthreads();

  float rowmax[2][4];
#pragma unroll
  for (int mf = 0; mf < 2; ++mf)
#pragma unroll
    for (int r = 0; r < 4; ++r) {
      const float4* rp = (const float4*)(red_max + (mf * 16 + lg * 4 + r) * 8);
      float4 x = rp[0], y = rp[1];
      rowmax[mf][r] = fmaxf(fmaxf(fmaxf(x.x, x.y), fmaxf(x.z, x.w)),
                            fmaxf(fmaxf(y.x, y.y), fmaxf(y.z, y.w)));
    }

  // wave-local sum of exp
  float rsum[2][4];
#pragma unroll
  for (int mf = 0; mf < 2; ++mf)
#pragma unroll
    for (int r = 0; r < 4; ++r) rsum[mf][r] = 0.f;
#pragma unroll
  for (int mf = 0; mf < 2; ++mf)
#pragma unroll
    for (int nf = 0; nf < 8; ++nf)
#pragma unroll
      for (int r = 0; r < 4; ++r)
        rsum[mf][r] += vmask[nf] ? __expf(acc[mf][nf][r] - rowmax[mf][r]) : 0.f;
#pragma unroll
  for (int s = 1; s < 16; s <<= 1)
#pragma unroll
    for (int mf = 0; mf < 2; ++mf)
#pragma unroll
      for (int r = 0; r < 4; ++r) rsum[mf][r] += __shfl_xor(rsum[mf][r], s);
  if (bl == 0)
#pragma unroll
    for (int mf = 0; mf < 2; ++mf)
#pragma unroll
      for (int r = 0; r < 4; ++r) red_sum[(mf * 16 + lg * 4 + r) * 8 + wave] = rsum[mf][r];
  __syncthreads();

#pragma unroll
  for (int mf = 0; mf < 2; ++mf)
#pragma unroll
    for (int r = 0; r < 4; ++r) {
      const float4* rp = (const float4*)(red_sum + (mf * 16 + lg * 4 + r) * 8);
      float4 x = rp[0], y = rp[1];
      float S = ((x.x + x.y) + (x.z + x.w)) + ((y.x + y.y) + (y.z + y.w));
      const float lse = rowmax[mf][r] + __logf(S);
      const int row = r0 + mf * 16 + lg * 4 + r;
#pragma unroll
      for (int nf = 0; nf < 8; ++nf) {
        const int col = wave * 128 + nf * 16 + bl;
        if (vmask[nf]) out[(size_t)row * OUT_DIM + col] = acc[mf][nf][r] - lse;
      }
    }
}

extern "C" void kernel_launch(void* const* d_in, const int* in_sizes, int n_in,
                              void* d_out, int out_size, void* d_ws, size_t ws_size,
                              hipStream_t stream) {
  const float* hist = (const float*)d_in[0];   // [4096][128]
  const float* img  = (const float*)d_in[1];   // [8192][128]
  const float* W    = (const float*)d_in[2];   // [1000][128]
  const float* bias = (const float*)d_in[3];   // [1000]
  float* out = (float*)d_out;                  // [8192][1000]

  char* ws = (char*)d_ws;
  // ws layout (~18.8 MiB):
  __bf16* hist_b  = (__bf16*)(ws);                         // 1 MiB
  __bf16* histT_b = (__bf16*)(ws + (1 << 20));             // 1 MiB
  float* sspart   = (float*)(ws + (2 << 20));              // 128 KiB [4][B]
  float* zpart    = (float*)(ws + (2 << 20) + (128 << 10));// 128 KiB [4][B]
  float* hvpart   = (float*)(ws + (2 << 20) + (256 << 10));// 16 MiB  [4][B][128]
  char* wsplit    = ws + (2 << 20) + (256 << 10) + (size_t)4 * B_DIM * 128 * 4;
  __bf16* W_hi    = (__bf16*)(wsplit);                     // 250 KiB
  __bf16* W_lo    = (__bf16*)(wsplit + 256000);            // 250 KiB

  k_prep<<<dim3(128), dim3(256), 0, stream>>>(hist, hist_b, histT_b);
  k_wprep<<<dim3(125), dim3(256), 0, stream>>>(W, W_hi, W_lo);
  k_norms<<<dim3(64, 4), dim3(512), 0, stream>>>(img, hist_b, sspart);
  k_attn<<<dim3(64, 4), dim3(512), 0, stream>>>(img, hist_b, histT_b, sspart, hvpart, zpart);
  k_scores2<<<dim3(256), dim3(512), 0, stream>>>(img, hvpart, zpart, W_hi, W_lo, bias, out);
}